// Round 12
// baseline (289.511 us; speedup 1.0000x reference)
//
#include <hip/hip_runtime.h>

// Problem constants (B=16, DIM=256, H=W=56, NH=8, HD=32, WS=7)
#define BATCH 16
#define DIM 256
#define HH 56
#define WW 56
#define HWP 3136            // 56*56
#define M_TOT 50176         // BATCH*HWP
#define NQKV 768            // 3*DIM
#define NHEADS 8
#define HDIM 32
#define NWIN 49             // 7*7
// workspace offsets (bytes)
#define QKV_BYTES   77070336ull   // M_TOT*NQKV*2 (bf16)
#define XT_OFF      77070336ull
#define XT_BYTES    25690112ull   // M_TOT*DIM*2
#define WQT_OFF    102760448ull
#define PWB_OFF    103153664ull
#define FCONV_OFF  103284736ull   // bf16 fconv: 288*HWP*BATCH*2 = 28901376
#define BIAS_OFF   132186112ull   // f32 [8][64][64] = 131072 B (ws >= 212 MB proven R2-R4)

typedef float f32x4 __attribute__((ext_vector_type(4)));
typedef short short8 __attribute__((ext_vector_type(8)));
typedef unsigned short ushort4v __attribute__((ext_vector_type(4)));

__device__ __forceinline__ short f2bf(float f) {
    unsigned u = __float_as_uint(f);
    u += 0x7fffu + ((u >> 16) & 1u);   // RNE
    return (short)(u >> 16);
}
__device__ __forceinline__ float bf2f(unsigned short u) {
    return __uint_as_float(((unsigned)u) << 16);
}
__device__ __forceinline__ unsigned pack2bf(float lo, float hi) {
    unsigned ul = __float_as_uint(lo); ul += 0x7fffu + ((ul >> 16) & 1u);
    unsigned uh = __float_as_uint(hi); uh += 0x7fffu + ((uh >> 16) & 1u);
    return (ul >> 16) | (uh & 0xffff0000u);
}
__device__ __forceinline__ int div7(int n) { return (n * 9363) >> 16; }  // exact for 0..63

// ---------------------------------------------------------------------------
// Kernel T0: x (B,C,HW) fp32 -> xt (B*HW, C) bf16.
__global__ __launch_bounds__(256) void xpose_kernel(const float* __restrict__ x,
                                                    unsigned short* __restrict__ xt) {
    __shared__ unsigned short tls[64 * 448];   // [ch][px'] swizzled, 56 KB
    const int tid = threadIdx.x;
    const int p0 = blockIdx.x * 448;
    const int k0 = blockIdx.y * 64;
    const int b  = blockIdx.z;
    const float* xb = x + ((size_t)b * DIM + k0) * HWP + p0;
    #pragma unroll
    for (int pass = 0; pass < 28; ++pass) {
        int idx = tid + pass * 256;            // float4 index (64*112 total)
        int ch = idx / 112, px4 = idx - ch * 112;
        float4 v = *(const float4*)(xb + (size_t)ch * HWP + px4 * 4);
        int px4s = px4 ^ ((ch >> 3) & 7);
        ushort4v s;
        s[0] = (unsigned short)f2bf(v.x); s[1] = (unsigned short)f2bf(v.y);
        s[2] = (unsigned short)f2bf(v.z); s[3] = (unsigned short)f2bf(v.w);
        *(ushort4v*)&tls[ch * 448 + px4s * 4] = s;
    }
    __syncthreads();
    unsigned short* xto = xt + ((size_t)b * HWP + p0) * DIM + k0;
    #pragma unroll
    for (int q = 0; q < 14; ++q) {
        int idx = tid + q * 256;               // uint4 index (3584 total)
        int px = idx >> 3, j8 = (idx & 7) * 8;
        int key = (j8 >> 3) & 7;
        int pxs = ((px >> 2) ^ key) * 4 + (px & 3);
        unsigned r[4];
        #pragma unroll
        for (int jj = 0; jj < 4; ++jj) {
            unsigned lo = tls[(j8 + 2 * jj) * 448 + pxs];
            unsigned hi = tls[(j8 + 2 * jj + 1) * 448 + pxs];
            r[jj] = lo | (hi << 16);
        }
        uint4 o; o.x = r[0]; o.y = r[1]; o.z = r[2]; o.w = r[3];
        *(uint4*)(xto + (size_t)px * DIM + j8) = o;
    }
}

// ---------------------------------------------------------------------------
// Kernel T1: blocks 0..47: wq -> wqt (j,k) bf16; 48..63: proj_w cast;
//            blocks 64..71: bias+mask table biasT[h][64][64] f32.
__global__ __launch_bounds__(256) void prep_kernel(const float* __restrict__ wq,
                                                   const float* __restrict__ pw,
                                                   const float* __restrict__ rpb,
                                                   unsigned short* __restrict__ wqt,
                                                   unsigned short* __restrict__ pwb,
                                                   float* __restrict__ biasT) {
    const int tid = threadIdx.x;
    const int bid = blockIdx.x;
    if (bid < 48) {
        __shared__ float t[64][65];
        const int j0 = (bid >> 2) * 64, k0 = (bid & 3) * 64;
        #pragma unroll
        for (int kk = tid >> 6; kk < 64; kk += 4)
            t[kk][tid & 63] = wq[(size_t)(k0 + kk) * NQKV + j0 + (tid & 63)];
        __syncthreads();
        const int jj = tid >> 2, c16 = (tid & 3) * 16;
        unsigned short* dst = wqt + (size_t)(j0 + jj) * DIM + k0 + c16;
        #pragma unroll
        for (int i = 0; i < 16; ++i) dst[i] = (unsigned short)f2bf(t[c16 + i][jj]);
    } else if (bid < 64) {
        const int base = (bid - 48) * 4096 + tid;
        #pragma unroll
        for (int i = 0; i < 16; ++i)
            pwb[base + i * 256] = (unsigned short)f2bf(pw[base + i * 256]);
    } else {
        const int h = bid - 64;
        #pragma unroll
        for (int i = 0; i < 16; ++i) {
            int idx = tid + i * 256;
            int n = idx >> 6, m = idx & 63;
            float v = -1e30f;
            if (n < 49 && m < 49) {
                int nd = div7(n), md = div7(m);
                int ii = (nd - md + 6) * 13 + ((n - nd * 7) - (m - md * 7) + 6);
                v = rpb[ii * NHEADS + h];
            }
            biasT[h * 4096 + idx] = v;
        }
    }
}

// ---------------------------------------------------------------------------
// Kernel A (v3, LDS-free direct-frag MFMA): qkv[m][j] = xt[m][:] . wqt[j][:] + bq
// Both operands K-contiguous bf16 -> fragments loaded straight from global.
// Zero barriers; one-step register ping-pong prefetch (all static indices).
__global__ __launch_bounds__(256) void qkv_gemm(const unsigned short* __restrict__ xt,
                                                const unsigned short* __restrict__ wqt,
                                                const float* __restrict__ bq,
                                                unsigned short* __restrict__ qkv) {
    const int bidx = blockIdx.x;
    const int wg = (bidx & 7) * 294 + (bidx >> 3);
    const int jt = wg % 6, mt = wg / 6;
    const int m0 = mt * 128, j0 = jt * 128;

    const int tid = threadIdx.x;
    const int lane = tid & 63;
    const int wave = tid >> 6;
    const int wr = wave >> 1, wc = wave & 1;
    const int r = lane & 15, q = lane >> 4;

    const unsigned short* ap[4];
    const unsigned short* bp[4];
    #pragma unroll
    for (int f = 0; f < 4; ++f) {
        ap[f] = xt  + (size_t)(m0 + wr * 64 + f * 16 + r) * DIM + q * 8;
        bp[f] = wqt + (size_t)(j0 + wc * 64 + f * 16 + r) * DIM + q * 8;
    }

    f32x4 acc[4][4];
    #pragma unroll
    for (int i = 0; i < 4; ++i)
        #pragma unroll
        for (int j = 0; j < 4; ++j) acc[i][j] = (f32x4){0.f, 0.f, 0.f, 0.f};

    short8 A0[4][2], B0[4][2], A1[4][2], B1[4][2];

    auto LOAD0 = [&](int K0) {
        #pragma unroll
        for (int f = 0; f < 4; ++f) {
            A0[f][0] = *(const short8*)(ap[f] + K0);
            A0[f][1] = *(const short8*)(ap[f] + K0 + 32);
            B0[f][0] = *(const short8*)(bp[f] + K0);
            B0[f][1] = *(const short8*)(bp[f] + K0 + 32);
        }
    };
    auto LOAD1 = [&](int K0) {
        #pragma unroll
        for (int f = 0; f < 4; ++f) {
            A1[f][0] = *(const short8*)(ap[f] + K0);
            A1[f][1] = *(const short8*)(ap[f] + K0 + 32);
            B1[f][0] = *(const short8*)(bp[f] + K0);
            B1[f][1] = *(const short8*)(bp[f] + K0 + 32);
        }
    };
    auto STEP0 = [&]() {
        #pragma unroll
        for (int ks = 0; ks < 2; ++ks)
            #pragma unroll
            for (int fm = 0; fm < 4; ++fm)
                #pragma unroll
                for (int fj = 0; fj < 4; ++fj)
                    acc[fm][fj] = __builtin_amdgcn_mfma_f32_16x16x32_bf16(
                        A0[fm][ks], B0[fj][ks], acc[fm][fj], 0, 0, 0);
    };
    auto STEP1 = [&]() {
        #pragma unroll
        for (int ks = 0; ks < 2; ++ks)
            #pragma unroll
            for (int fm = 0; fm < 4; ++fm)
                #pragma unroll
                for (int fj = 0; fj < 4; ++fj)
                    acc[fm][fj] = __builtin_amdgcn_mfma_f32_16x16x32_bf16(
                        A1[fm][ks], B1[fj][ks], acc[fm][fj], 0, 0, 0);
    };

    LOAD0(0);
    LOAD1(64);
    STEP0();          // k0 = 0
    LOAD0(128);
    STEP1();          // k0 = 64
    LOAD1(192);
    STEP0();          // k0 = 128
    STEP1();          // k0 = 192

    #pragma unroll
    for (int fm = 0; fm < 4; ++fm) {
        const int mbase = m0 + wr * 64 + fm * 16 + q * 4;
        #pragma unroll
        for (int fj = 0; fj < 4; ++fj) {
            const int j = j0 + wc * 64 + fj * 16 + r;
            const float bias = bq[j];
            unsigned short* op = qkv + (size_t)mbase * NQKV + j;
            #pragma unroll
            for (int rg = 0; rg < 4; ++rg)
                op[(size_t)rg * NQKV] = (unsigned short)f2bf(acc[fm][fj][rg] + bias);
        }
    }
}

// ---------------------------------------------------------------------------
// Kernel B: f_conv[b, g*9+o, p] = sum_c fc_w[o,c]*bf2f(qkv[b,p,c*32+g]) + fc_b[o]
__global__ __launch_bounds__(256) void fc_kernel(const unsigned short* __restrict__ qkv,
                                                 const float* __restrict__ fc_w,
                                                 const float* __restrict__ fc_b,
                                                 unsigned short* __restrict__ fconv) {
    __shared__ unsigned short f[16 * 768];   // 24 KB
    __shared__ float ob[16][289];
    __shared__ float w[9][24];
    __shared__ float bsh[9];
    const int tid = threadIdx.x;
    if (tid < 216) w[tid / 24][tid % 24] = fc_w[tid];
    if (tid < 9) bsh[tid] = fc_b[tid];
    const int p0 = blockIdx.x * 16;
    const int b  = blockIdx.y;
    const uint4* src = (const uint4*)(qkv + ((size_t)b * HWP + p0) * NQKV);
    uint4* dstf = (uint4*)f;
    #pragma unroll
    for (int i = 0; i < 6; ++i) dstf[tid + i * 256] = src[tid + i * 256];
    __syncthreads();
    #pragma unroll
    for (int it = 0; it < 2; ++it) {
        const int item = tid + it * 256;
        const int pp = item >> 5, g = item & 31;
        const unsigned short* fr = f + pp * 768 + g;
        float acc[9];
        #pragma unroll
        for (int o = 0; o < 9; ++o) acc[o] = bsh[o];
        #pragma unroll
        for (int c = 0; c < 24; ++c) {
            float v = bf2f(fr[c * 32]);
            #pragma unroll
            for (int o = 0; o < 9; ++o) acc[o] += w[o][c] * v;
        }
        #pragma unroll
        for (int o = 0; o < 9; ++o) ob[pp][g * 9 + o] = acc[o];
    }
    __syncthreads();
    unsigned short* og = fconv + (size_t)b * 288 * HWP + p0;
    for (int i = tid; i < 288 * 16; i += 256) {
        int ch = i >> 4, pp = i & 15;
        og[(size_t)ch * HWP + pp] = (unsigned short)f2bf(ob[pp][ch]);
    }
}

// ---------------------------------------------------------------------------
// Kernel C (v4): grouped 3x3 conv, lane = output column.
__global__ __launch_bounds__(256) void conv_kernel(const unsigned short* __restrict__ fconv,
                                                   const float* __restrict__ dep_w,
                                                   const float* __restrict__ rate2p,
                                                   float* __restrict__ out) {
    __shared__ unsigned short hal[9][10][64];  // 11520 B
    __shared__ float wfl[81][8];               // [o*9+ky*3+kx][c8]
    const int tid = threadIdx.x;
    const int strip = blockIdx.x;              // 0..6 (8 rows each)
    const int g = blockIdx.y, b = blockIdx.z;

    for (int i = tid; i < 648; i += 256) {
        int ok = i >> 3, c8 = i & 7;
        wfl[ok][c8] = dep_w[(size_t)(g * 8 + c8) * 81 + ok];
    }
    const unsigned short* fp = fconv + ((size_t)b * 288 + g * 9) * HWP;
    const int y0 = strip * 8 - 1;
    for (int i = tid; i < 5760; i += 256) {
        int col = i & 63;
        int rest = i >> 6;                     // 0..89
        int o = rest / 10, y = rest - o * 10;
        int gy = y0 + y, gx = col - 1;
        unsigned short v = 0;
        if (gy >= 0 && gy < HH && (unsigned)gx < WW)
            v = fp[(size_t)o * HWP + gy * WW + gx];
        hal[o][y][col] = v;
    }
    __syncthreads();

    const int x = tid & 63;
    const int w = tid >> 6;                    // wave -> out rows 2w, 2w+1
    const int e = x & ~1;
    const bool odd = (x & 1) != 0;
    float acc[2][8] = {};
    for (int o = 0; o < 9; ++o) {
        float V[4][3];
        #pragma unroll
        for (int h = 0; h < 4; ++h) {
            const unsigned short* hr = &hal[o][2 * w + h][e];
            unsigned D0 = *(const unsigned*)hr;
            unsigned D1 = *(const unsigned*)(hr + 2);
            float a0 = __uint_as_float(D0 << 16);
            float a1 = __uint_as_float(D0 & 0xffff0000u);
            float a2 = __uint_as_float(D1 << 16);
            float a3 = __uint_as_float(D1 & 0xffff0000u);
            V[h][0] = odd ? a1 : a0;
            V[h][1] = odd ? a2 : a1;
            V[h][2] = odd ? a3 : a2;
        }
        #pragma unroll
        for (int ky = 0; ky < 3; ++ky)
            #pragma unroll
            for (int kx = 0; kx < 3; ++kx) {
                f32x4 w0 = *(const f32x4*)&wfl[o * 9 + ky * 3 + kx][0];
                f32x4 w1 = *(const f32x4*)&wfl[o * 9 + ky * 3 + kx][4];
                #pragma unroll
                for (int j = 0; j < 2; ++j) {
                    const float vv = V[j + ky][kx];
                    acc[j][0] += vv * w0[0]; acc[j][1] += vv * w0[1];
                    acc[j][2] += vv * w0[2]; acc[j][3] += vv * w0[3];
                    acc[j][4] += vv * w1[0]; acc[j][5] += vv * w1[1];
                    acc[j][6] += vv * w1[2]; acc[j][7] += vv * w1[3];
                }
            }
    }
    if (x < WW) {
        const float r2 = rate2p[0];
        #pragma unroll
        for (int j = 0; j < 2; ++j) {
            const int y = strip * 8 + 2 * w + j;
            #pragma unroll
            for (int c8 = 0; c8 < 8; ++c8)
                out[((size_t)b * DIM + g * 8 + c8) * HWP + y * WW + x] = r2 * acc[j][c8];
        }
    }
}

// ---------------------------------------------------------------------------
// Kernel D (v2): one block = one window, 8 waves = 8 heads. V fragments direct
// from global (clamped rows are zeroed by the bias mask through softmax);
// bias+mask from precomputed biasT (coalesced L2 loads). LDS = PL only; no
// barriers at all.
__global__ __launch_bounds__(512) void attn_kernel(const unsigned short* __restrict__ qkv,
                                                   const float* __restrict__ biasT,
                                                   unsigned short* __restrict__ obuf) {
    __shared__ __attribute__((aligned(16))) short PL[8 * 16 * 72]; // per-wave [16][72] 18 KB
    const int tid = threadIdx.x;
    const int win = blockIdx.x;
    const int b = win >> 6, wrw = win & 63;
    const int wy = wrw >> 3, wx = wrw & 7;
    const size_t wbase = (size_t)b * HWP + (size_t)(wy * 7) * WW + wx * 7;

    const int lane = tid & 63;
    const int h = tid >> 6;
    const int c = lane & 15, qg = lane >> 4;

    // Q A-frags / K B-frags direct from global (rows clamped to 48)
    short8 aq[4], bk[4];
    #pragma unroll
    for (int f = 0; f < 4; ++f) {
        int t = f * 16 + c; if (t > 48) t = 48;
        const int tq = div7(t), tr = t - tq * 7;
        const unsigned short* base = qkv + (wbase + tq * WW + tr) * NQKV + h * 32 + qg * 8;
        aq[f] = *(const short8*)base;
        bk[f] = *(const short8*)(base + 256);
    }
    // V B-frags direct from global: bv[ks][fo][i] = V[pix=ks*32+qg*8+i][h*32+fo*16+c]
    short8 bv[2][2];
    #pragma unroll
    for (int ks = 0; ks < 2; ++ks)
        #pragma unroll
        for (int i = 0; i < 8; ++i) {
            int pix = ks * 32 + qg * 8 + i; if (pix > 48) pix = 48;
            const int pd = div7(pix);
            const unsigned short* vp = qkv + (wbase + pd * WW + (pix - pd * 7)) * NQKV
                                           + 512 + h * 32 + c;
            bv[ks][0][i] = (short)vp[0];
            bv[ks][1][i] = (short)vp[16];
        }

    const float scale = 0.17677669529663687f;
    const float* bt = biasT + h * 4096;
    short* pw = PL + h * 16 * 72;

    #pragma unroll
    for (int fm = 0; fm < 4; ++fm) {
        f32x4 s[4];
        #pragma unroll
        for (int fj = 0; fj < 4; ++fj)
            s[fj] = __builtin_amdgcn_mfma_f32_16x16x32_bf16(aq[fm], bk[fj],
                                                            (f32x4){0.f,0.f,0.f,0.f}, 0, 0, 0);
        float p[4][4];
        #pragma unroll
        for (int reg = 0; reg < 4; ++reg) {
            const float* brow = bt + (fm * 16 + qg * 4 + reg) * 64;
            #pragma unroll
            for (int fj = 0; fj < 4; ++fj)
                p[fj][reg] = s[fj][reg] * scale + brow[fj * 16 + c];
        }
        float inv[4];
        #pragma unroll
        for (int reg = 0; reg < 4; ++reg) {
            float mx = fmaxf(fmaxf(p[0][reg], p[1][reg]), fmaxf(p[2][reg], p[3][reg]));
            mx = fmaxf(mx, __shfl_xor(mx, 1));
            mx = fmaxf(mx, __shfl_xor(mx, 2));
            mx = fmaxf(mx, __shfl_xor(mx, 4));
            mx = fmaxf(mx, __shfl_xor(mx, 8));
            float sum = 0.f;
            #pragma unroll
            for (int fj = 0; fj < 4; ++fj) {
                float e = __expf(p[fj][reg] - mx);
                p[fj][reg] = e; sum += e;
            }
            sum += __shfl_xor(sum, 1);
            sum += __shfl_xor(sum, 2);
            sum += __shfl_xor(sum, 4);
            sum += __shfl_xor(sum, 8);
            inv[reg] = 1.0f / sum;
        }
        #pragma unroll
        for (int fj = 0; fj < 4; ++fj)
            #pragma unroll
            for (int reg = 0; reg < 4; ++reg) {
                float v = p[fj][reg] * inv[reg];
                float o = __shfl_xor(v, 1);
                unsigned packed = (c & 1) ? pack2bf(o, v) : pack2bf(v, o);
                if ((c & 1) == 0)
                    *(unsigned*)&pw[(qg * 4 + reg) * 72 + fj * 16 + c] = packed;
            }
        short8 ap0 = *(const short8*)&pw[c * 72 + 0 * 32 + qg * 8];
        short8 ap1 = *(const short8*)&pw[c * 72 + 1 * 32 + qg * 8];
        #pragma unroll
        for (int fo = 0; fo < 2; ++fo) {
            f32x4 o4 = __builtin_amdgcn_mfma_f32_16x16x32_bf16(ap0, bv[0][fo],
                                                               (f32x4){0.f,0.f,0.f,0.f}, 0, 0, 0);
            o4 = __builtin_amdgcn_mfma_f32_16x16x32_bf16(ap1, bv[1][fo], o4, 0, 0, 0);
            #pragma unroll
            for (int reg = 0; reg < 4; ++reg) {
                int n = fm * 16 + qg * 4 + reg;
                if (n < 49) {
                    int nd = div7(n), nm = n - nd * 7;
                    obuf[(wbase + nd * WW + nm) * DIM + h * 32 + fo * 16 + c] =
                        (unsigned short)f2bf(o4[reg]);
                }
            }
        }
    }
}

// ---------------------------------------------------------------------------
// Kernel E (MFMA): out[b,c,p] += rate1 * (obuf @ proj_w^T + pb)
__global__ __launch_bounds__(256) void proj_gemm(const unsigned short* __restrict__ obuf,
                                                 const unsigned short* __restrict__ pwb,
                                                 const float* __restrict__ pb,
                                                 const float* __restrict__ rate1p,
                                                 float* __restrict__ out) {
    __shared__ short M_lds[128 * 64];
    __shared__ short C_lds[128 * 64];
    const int bidx = blockIdx.x;
    const int wg = (bidx & 7) * 98 + (bidx >> 3);   // grid 784 = 8*98
    const int ct = wg & 1, mt = wg >> 1;
    const int m0 = mt * 128, c0 = ct * 128;

    const int tid = threadIdx.x;
    const int lane = tid & 63;
    const int wave = tid >> 6;
    const int wr = wave >> 1, wc = wave & 1;

    const int srow = tid & 127;
    const int kh = tid >> 7;
    const unsigned short* mptr = obuf + (size_t)(m0 + srow) * DIM + kh * 32;
    const unsigned short* cptr = pwb  + (size_t)(c0 + srow) * DIM + kh * 32;

    f32x4 acc[4][4];
    #pragma unroll
    for (int i = 0; i < 4; ++i)
        #pragma unroll
        for (int j = 0; j < 4; ++j) acc[i][j] = (f32x4){0.f, 0.f, 0.f, 0.f};

    const int r = lane & 15, q = lane >> 4;
    for (int k0 = 0; k0 < DIM; k0 += 64) {
        __syncthreads();
        #pragma unroll
        for (int g = 0; g < 4; ++g) {
            *(short8*)&M_lds[srow * 64 + 8 * ((kh * 4 + g) ^ (srow & 7))] =
                *(const short8*)(mptr + k0 + g * 8);
            *(short8*)&C_lds[srow * 64 + 8 * ((kh * 4 + g) ^ (srow & 7))] =
                *(const short8*)(cptr + k0 + g * 8);
        }
        __syncthreads();
        #pragma unroll
        for (int ks = 0; ks < 2; ++ks) {
            short8 cf[4], mf[4];
            #pragma unroll
            for (int f = 0; f < 4; ++f) {
                int crow = wr * 64 + f * 16 + r;
                cf[f] = *(const short8*)&C_lds[crow * 64 + 8 * ((ks * 4 + q) ^ (crow & 7))];
                int mrow = wc * 64 + f * 16 + r;
                mf[f] = *(const short8*)&M_lds[mrow * 64 + 8 * ((ks * 4 + q) ^ (mrow & 7))];
            }
            #pragma unroll
            for (int fc = 0; fc < 4; ++fc)
                #pragma unroll
                for (int fm2 = 0; fm2 < 4; ++fm2)
                    acc[fc][fm2] = __builtin_amdgcn_mfma_f32_16x16x32_bf16(
                        cf[fc], mf[fm2], acc[fc][fm2], 0, 0, 0);
        }
    }
    const float r1 = rate1p[0];
    size_t boff[4];
    #pragma unroll
    for (int fm2 = 0; fm2 < 4; ++fm2) {
        int mb = m0 + wc * 64 + fm2 * 16 + r;
        boff[fm2] = (size_t)(mb / HWP) * DIM * HWP + (mb % HWP);
    }
    #pragma unroll
    for (int fc = 0; fc < 4; ++fc) {
        #pragma unroll
        for (int reg = 0; reg < 4; ++reg) {
            const int cc = c0 + wr * 64 + fc * 16 + q * 4 + reg;
            const float bias = pb[cc];
            #pragma unroll
            for (int fm2 = 0; fm2 < 4; ++fm2) {
                float* dst = out + boff[fm2] + (size_t)cc * HWP;
                *dst = *dst + r1 * (acc[fc][fm2][reg] + bias);
            }
        }
    }
}

// ---------------------------------------------------------------------------
extern "C" void kernel_launch(void* const* d_in, const int* in_sizes, int n_in,
                              void* d_out, int out_size, void* d_ws, size_t ws_size,
                              hipStream_t stream) {
    const float* x      = (const float*)d_in[0];
    const float* qkv_w  = (const float*)d_in[1];
    const float* qkv_b  = (const float*)d_in[2];
    const float* fc_w   = (const float*)d_in[3];
    const float* fc_b   = (const float*)d_in[4];
    const float* dep_w  = (const float*)d_in[5];
    const float* proj_w = (const float*)d_in[6];
    const float* proj_b = (const float*)d_in[7];
    const float* rpb    = (const float*)d_in[8];
    const float* rate1  = (const float*)d_in[9];
    const float* rate2  = (const float*)d_in[10];
    float* out = (float*)d_out;

    unsigned short* qkv   = (unsigned short*)d_ws;
    unsigned short* xt    = (unsigned short*)((char*)d_ws + XT_OFF);
    unsigned short* wqt   = (unsigned short*)((char*)d_ws + WQT_OFF);
    unsigned short* pwb   = (unsigned short*)((char*)d_ws + PWB_OFF);
    unsigned short* fconv = (unsigned short*)((char*)d_ws + FCONV_OFF);
    float*          biasT = (float*)((char*)d_ws + BIAS_OFF);
    unsigned short* obuf  = fconv;  // reused after conv_kernel consumes fconv

    xpose_kernel<<<dim3(7, 4, BATCH), 256, 0, stream>>>(x, xt);
    prep_kernel<<<dim3(72), 256, 0, stream>>>(qkv_w, proj_w, rpb, wqt, pwb, biasT);
    qkv_gemm<<<dim3(2352), 256, 0, stream>>>(xt, wqt, qkv_b, qkv);
    fc_kernel<<<dim3(HWP / 16, BATCH), 256, 0, stream>>>(qkv, fc_w, fc_b, fconv);
    conv_kernel<<<dim3(7, 32, BATCH), 256, 0, stream>>>(fconv, dep_w, rate2, out);
    attn_kernel<<<dim3(1024), 512, 0, stream>>>(qkv, biasT, obuf);
    proj_gemm<<<dim3(784), 256, 0, stream>>>(obuf, pwb, proj_b, rate1, out);
}

// Round 13
// 238.013 us; speedup vs baseline: 1.2164x; 1.2164x over previous
//
#include <hip/hip_runtime.h>

// Problem constants (B=16, DIM=256, H=W=56, NH=8, HD=32, WS=7)
#define BATCH 16
#define DIM 256
#define HH 56
#define WW 56
#define HWP 3136            // 56*56
#define M_TOT 50176         // BATCH*HWP
#define NQKV 768            // 3*DIM
#define NHEADS 8
#define HDIM 32
#define NWIN 49             // 7*7
// workspace offsets (bytes)
#define QKV_BYTES   77070336ull   // M_TOT*NQKV*2 (bf16)
#define XT_OFF      77070336ull
#define XT_BYTES    25690112ull   // M_TOT*DIM*2
#define WQT_OFF    102760448ull
#define PWB_OFF    103153664ull
#define FCONV_OFF  103284736ull   // bf16 fconv: 288*HWP*BATCH*2 = 28901376
#define BIAS_OFF   132186112ull   // f32 [8][64][64] = 131072 B

typedef float f32x4 __attribute__((ext_vector_type(4)));
typedef short short8 __attribute__((ext_vector_type(8)));
typedef unsigned short ushort4v __attribute__((ext_vector_type(4)));

__device__ __forceinline__ short f2bf(float f) {
    unsigned u = __float_as_uint(f);
    u += 0x7fffu + ((u >> 16) & 1u);   // RNE
    return (short)(u >> 16);
}
__device__ __forceinline__ float bf2f(unsigned short u) {
    return __uint_as_float(((unsigned)u) << 16);
}
__device__ __forceinline__ unsigned pack2bf(float lo, float hi) {
    unsigned ul = __float_as_uint(lo); ul += 0x7fffu + ((ul >> 16) & 1u);
    unsigned uh = __float_as_uint(hi); uh += 0x7fffu + ((uh >> 16) & 1u);
    return (ul >> 16) | (uh & 0xffff0000u);
}
__device__ __forceinline__ int div7(int n) { return (n * 9363) >> 16; }  // exact for 0..63

// async global->LDS, 16B per lane; LDS dest = uniform base + lane*16
__device__ __forceinline__ void gld16(const unsigned short* g, unsigned short* l) {
    __builtin_amdgcn_global_load_lds(
        (const __attribute__((address_space(1))) void*)g,
        (__attribute__((address_space(3))) void*)l, 16, 0, 0);
}

// ---------------------------------------------------------------------------
// Kernel T0: x (B,C,HW) fp32 -> xt (B*HW, C) bf16.
__global__ __launch_bounds__(256) void xpose_kernel(const float* __restrict__ x,
                                                    unsigned short* __restrict__ xt) {
    __shared__ unsigned short tls[64 * 448];   // [ch][px'] swizzled, 56 KB
    const int tid = threadIdx.x;
    const int p0 = blockIdx.x * 448;
    const int k0 = blockIdx.y * 64;
    const int b  = blockIdx.z;
    const float* xb = x + ((size_t)b * DIM + k0) * HWP + p0;
    #pragma unroll
    for (int pass = 0; pass < 28; ++pass) {
        int idx = tid + pass * 256;            // float4 index (64*112 total)
        int ch = idx / 112, px4 = idx - ch * 112;
        float4 v = *(const float4*)(xb + (size_t)ch * HWP + px4 * 4);
        int px4s = px4 ^ ((ch >> 3) & 7);
        ushort4v s;
        s[0] = (unsigned short)f2bf(v.x); s[1] = (unsigned short)f2bf(v.y);
        s[2] = (unsigned short)f2bf(v.z); s[3] = (unsigned short)f2bf(v.w);
        *(ushort4v*)&tls[ch * 448 + px4s * 4] = s;
    }
    __syncthreads();
    unsigned short* xto = xt + ((size_t)b * HWP + p0) * DIM + k0;
    #pragma unroll
    for (int q = 0; q < 14; ++q) {
        int idx = tid + q * 256;               // uint4 index (3584 total)
        int px = idx >> 3, j8 = (idx & 7) * 8;
        int key = (j8 >> 3) & 7;
        int pxs = ((px >> 2) ^ key) * 4 + (px & 3);
        unsigned r[4];
        #pragma unroll
        for (int jj = 0; jj < 4; ++jj) {
            unsigned lo = tls[(j8 + 2 * jj) * 448 + pxs];
            unsigned hi = tls[(j8 + 2 * jj + 1) * 448 + pxs];
            r[jj] = lo | (hi << 16);
        }
        uint4 o; o.x = r[0]; o.y = r[1]; o.z = r[2]; o.w = r[3];
        *(uint4*)(xto + (size_t)px * DIM + j8) = o;
    }
}

// ---------------------------------------------------------------------------
// Kernel T1: blocks 0..47: wq -> wqt (j,k) bf16; 48..63: proj_w cast;
//            blocks 64..71: bias+mask table biasT[h][64][64] f32.
__global__ __launch_bounds__(256) void prep_kernel(const float* __restrict__ wq,
                                                   const float* __restrict__ pw,
                                                   const float* __restrict__ rpb,
                                                   unsigned short* __restrict__ wqt,
                                                   unsigned short* __restrict__ pwb,
                                                   float* __restrict__ biasT) {
    const int tid = threadIdx.x;
    const int bid = blockIdx.x;
    if (bid < 48) {
        __shared__ float t[64][65];
        const int j0 = (bid >> 2) * 64, k0 = (bid & 3) * 64;
        #pragma unroll
        for (int kk = tid >> 6; kk < 64; kk += 4)
            t[kk][tid & 63] = wq[(size_t)(k0 + kk) * NQKV + j0 + (tid & 63)];
        __syncthreads();
        const int jj = tid >> 2, c16 = (tid & 3) * 16;
        unsigned short* dst = wqt + (size_t)(j0 + jj) * DIM + k0 + c16;
        #pragma unroll
        for (int i = 0; i < 16; ++i) dst[i] = (unsigned short)f2bf(t[c16 + i][jj]);
    } else if (bid < 64) {
        const int base = (bid - 48) * 4096 + tid;
        #pragma unroll
        for (int i = 0; i < 16; ++i)
            pwb[base + i * 256] = (unsigned short)f2bf(pw[base + i * 256]);
    } else {
        const int h = bid - 64;
        #pragma unroll
        for (int i = 0; i < 16; ++i) {
            int idx = tid + i * 256;
            int n = idx >> 6, m = idx & 63;
            float v = -1e30f;
            if (n < 49 && m < 49) {
                int nd = div7(n), md = div7(m);
                int ii = (nd - md + 6) * 13 + ((n - nd * 7) - (m - md * 7) + 6);
                v = rpb[ii * NHEADS + h];
            }
            biasT[h * 4096 + idx] = v;
        }
    }
}

// ---------------------------------------------------------------------------
// Kernel A (v5): m97-style dbuf GEMM, BK=32, global_load_lds width-16 staging.
// LDS linear for the DMA; bank swizzle moved to pre-swizzled GLOBAL source:
// chunk ci -> row=ci>>2, content kgrp=(ci&3)^(row&3); frag reads XOR same key.
__global__ __launch_bounds__(256) void qkv_gemm(const unsigned short* __restrict__ xt,
                                                const unsigned short* __restrict__ wqt,
                                                const float* __restrict__ bq,
                                                unsigned short* __restrict__ qkv) {
    __shared__ __attribute__((aligned(16))) short A_lds[2][128 * 32];  // 16 KB
    __shared__ __attribute__((aligned(16))) short B_lds[2][128 * 32];  // 16 KB
    const int bidx = blockIdx.x;
    const int wg = (bidx & 7) * 294 + (bidx >> 3);
    const int jt = wg % 6, mt = wg / 6;
    const int m0 = mt * 128, j0 = jt * 128;

    const int tid = threadIdx.x;
    const int lane = tid & 63;
    const int wave = tid >> 6;
    const int wr = wave >> 1, wc = wave & 1;
    const int r = lane & 15, q = lane >> 4;

    // staging source pointers (pre-swizzled): 2 chunks-instrs per wave per matrix
    const unsigned short* aG[2];
    const unsigned short* bG[2];
    int lbase[2];
    #pragma unroll
    for (int t = 0; t < 2; ++t) {
        int ci = wave * 128 + t * 64 + lane;
        int srow = ci >> 2;
        int kgrp = (ci & 3) ^ (srow & 3);
        aG[t] = xt  + (size_t)(m0 + srow) * DIM + kgrp * 8;
        bG[t] = wqt + (size_t)(j0 + srow) * DIM + kgrp * 8;
        lbase[t] = (wave * 128 + t * 64) * 8;   // shorts
    }

    f32x4 acc[4][4];
    #pragma unroll
    for (int i = 0; i < 4; ++i)
        #pragma unroll
        for (int j = 0; j < 4; ++j) acc[i][j] = (f32x4){0.f, 0.f, 0.f, 0.f};

    // prologue stage k=0 into buf 0
    #pragma unroll
    for (int t = 0; t < 2; ++t) {
        gld16(aG[t], (unsigned short*)&A_lds[0][lbase[t]]);
        gld16(bG[t], (unsigned short*)&B_lds[0][lbase[t]]);
    }
    __syncthreads();

    #pragma unroll
    for (int k = 0; k < 8; ++k) {
        const int buf = k & 1;
        if (k < 7) {
            const int k0 = (k + 1) * 32;
            #pragma unroll
            for (int t = 0; t < 2; ++t) {
                gld16(aG[t] + k0, (unsigned short*)&A_lds[buf ^ 1][lbase[t]]);
                gld16(bG[t] + k0, (unsigned short*)&B_lds[buf ^ 1][lbase[t]]);
            }
        }
        short8 af[4], bfr[4];
        #pragma unroll
        for (int f = 0; f < 4; ++f) {
            int mrow = wr * 64 + f * 16 + r;
            af[f] = *(const short8*)&A_lds[buf][mrow * 32 + 8 * (q ^ (mrow & 3))];
            int nrow = wc * 64 + f * 16 + r;
            bfr[f] = *(const short8*)&B_lds[buf][nrow * 32 + 8 * (q ^ (nrow & 3))];
        }
        #pragma unroll
        for (int fm = 0; fm < 4; ++fm)
            #pragma unroll
            for (int fj = 0; fj < 4; ++fj)
                acc[fm][fj] = __builtin_amdgcn_mfma_f32_16x16x32_bf16(
                    af[fm], bfr[fj], acc[fm][fj], 0, 0, 0);
        __syncthreads();
    }

    #pragma unroll
    for (int fm = 0; fm < 4; ++fm) {
        const int mbase = m0 + wr * 64 + fm * 16 + q * 4;
        #pragma unroll
        for (int fj = 0; fj < 4; ++fj) {
            const int j = j0 + wc * 64 + fj * 16 + r;
            const float bias = bq[j];
            unsigned short* op = qkv + (size_t)mbase * NQKV + j;
            #pragma unroll
            for (int rg = 0; rg < 4; ++rg)
                op[(size_t)rg * NQKV] = (unsigned short)f2bf(acc[fm][fj][rg] + bias);
        }
    }
}

// ---------------------------------------------------------------------------
// Kernel B: f_conv[b, g*9+o, p] = sum_c fc_w[o,c]*bf2f(qkv[b,p,c*32+g]) + fc_b[o]
__global__ __launch_bounds__(256) void fc_kernel(const unsigned short* __restrict__ qkv,
                                                 const float* __restrict__ fc_w,
                                                 const float* __restrict__ fc_b,
                                                 unsigned short* __restrict__ fconv) {
    __shared__ unsigned short f[16 * 768];   // 24 KB
    __shared__ float ob[16][289];
    __shared__ float w[9][24];
    __shared__ float bsh[9];
    const int tid = threadIdx.x;
    if (tid < 216) w[tid / 24][tid % 24] = fc_w[tid];
    if (tid < 9) bsh[tid] = fc_b[tid];
    const int p0 = blockIdx.x * 16;
    const int b  = blockIdx.y;
    const uint4* src = (const uint4*)(qkv + ((size_t)b * HWP + p0) * NQKV);
    uint4* dstf = (uint4*)f;
    #pragma unroll
    for (int i = 0; i < 6; ++i) dstf[tid + i * 256] = src[tid + i * 256];
    __syncthreads();
    #pragma unroll
    for (int it = 0; it < 2; ++it) {
        const int item = tid + it * 256;
        const int pp = item >> 5, g = item & 31;
        const unsigned short* fr = f + pp * 768 + g;
        float acc[9];
        #pragma unroll
        for (int o = 0; o < 9; ++o) acc[o] = bsh[o];
        #pragma unroll
        for (int c = 0; c < 24; ++c) {
            float v = bf2f(fr[c * 32]);
            #pragma unroll
            for (int o = 0; o < 9; ++o) acc[o] += w[o][c] * v;
        }
        #pragma unroll
        for (int o = 0; o < 9; ++o) ob[pp][g * 9 + o] = acc[o];
    }
    __syncthreads();
    unsigned short* og = fconv + (size_t)b * 288 * HWP + p0;
    for (int i = tid; i < 288 * 16; i += 256) {
        int ch = i >> 4, pp = i & 15;
        og[(size_t)ch * HWP + pp] = (unsigned short)f2bf(ob[pp][ch]);
    }
}

// ---------------------------------------------------------------------------
// Kernel C (v4): grouped 3x3 conv, lane = output column.
__global__ __launch_bounds__(256) void conv_kernel(const unsigned short* __restrict__ fconv,
                                                   const float* __restrict__ dep_w,
                                                   const float* __restrict__ rate2p,
                                                   float* __restrict__ out) {
    __shared__ unsigned short hal[9][10][64];  // 11520 B
    __shared__ float wfl[81][8];               // [o*9+ky*3+kx][c8]
    const int tid = threadIdx.x;
    const int strip = blockIdx.x;              // 0..6 (8 rows each)
    const int g = blockIdx.y, b = blockIdx.z;

    for (int i = tid; i < 648; i += 256) {
        int ok = i >> 3, c8 = i & 7;
        wfl[ok][c8] = dep_w[(size_t)(g * 8 + c8) * 81 + ok];
    }
    const unsigned short* fp = fconv + ((size_t)b * 288 + g * 9) * HWP;
    const int y0 = strip * 8 - 1;
    for (int i = tid; i < 5760; i += 256) {
        int col = i & 63;
        int rest = i >> 6;                     // 0..89
        int o = rest / 10, y = rest - o * 10;
        int gy = y0 + y, gx = col - 1;
        unsigned short v = 0;
        if (gy >= 0 && gy < HH && (unsigned)gx < WW)
            v = fp[(size_t)o * HWP + gy * WW + gx];
        hal[o][y][col] = v;
    }
    __syncthreads();

    const int x = tid & 63;
    const int w = tid >> 6;                    // wave -> out rows 2w, 2w+1
    const int e = x & ~1;
    const bool odd = (x & 1) != 0;
    float acc[2][8] = {};
    for (int o = 0; o < 9; ++o) {
        float V[4][3];
        #pragma unroll
        for (int h = 0; h < 4; ++h) {
            const unsigned short* hr = &hal[o][2 * w + h][e];
            unsigned D0 = *(const unsigned*)hr;
            unsigned D1 = *(const unsigned*)(hr + 2);
            float a0 = __uint_as_float(D0 << 16);
            float a1 = __uint_as_float(D0 & 0xffff0000u);
            float a2 = __uint_as_float(D1 << 16);
            float a3 = __uint_as_float(D1 & 0xffff0000u);
            V[h][0] = odd ? a1 : a0;
            V[h][1] = odd ? a2 : a1;
            V[h][2] = odd ? a3 : a2;
        }
        #pragma unroll
        for (int ky = 0; ky < 3; ++ky)
            #pragma unroll
            for (int kx = 0; kx < 3; ++kx) {
                f32x4 w0 = *(const f32x4*)&wfl[o * 9 + ky * 3 + kx][0];
                f32x4 w1 = *(const f32x4*)&wfl[o * 9 + ky * 3 + kx][4];
                #pragma unroll
                for (int j = 0; j < 2; ++j) {
                    const float vv = V[j + ky][kx];
                    acc[j][0] += vv * w0[0]; acc[j][1] += vv * w0[1];
                    acc[j][2] += vv * w0[2]; acc[j][3] += vv * w0[3];
                    acc[j][4] += vv * w1[0]; acc[j][5] += vv * w1[1];
                    acc[j][6] += vv * w1[2]; acc[j][7] += vv * w1[3];
                }
            }
    }
    if (x < WW) {
        const float r2 = rate2p[0];
        #pragma unroll
        for (int j = 0; j < 2; ++j) {
            const int y = strip * 8 + 2 * w + j;
            #pragma unroll
            for (int c8 = 0; c8 < 8; ++c8)
                out[((size_t)b * DIM + g * 8 + c8) * HWP + y * WW + x] = r2 * acc[j][c8];
        }
    }
}

// ---------------------------------------------------------------------------
// Kernel D (v2): one block = one window, 8 waves = 8 heads. V direct from
// global; bias+mask from precomputed biasT; LDS = PL only; no barriers.
__global__ __launch_bounds__(512) void attn_kernel(const unsigned short* __restrict__ qkv,
                                                   const float* __restrict__ biasT,
                                                   unsigned short* __restrict__ obuf) {
    __shared__ __attribute__((aligned(16))) short PL[8 * 16 * 72]; // per-wave [16][72] 18 KB
    const int tid = threadIdx.x;
    const int win = blockIdx.x;
    const int b = win >> 6, wrw = win & 63;
    const int wy = wrw >> 3, wx = wrw & 7;
    const size_t wbase = (size_t)b * HWP + (size_t)(wy * 7) * WW + wx * 7;

    const int lane = tid & 63;
    const int h = tid >> 6;
    const int c = lane & 15, qg = lane >> 4;

    short8 aq[4], bk[4];
    #pragma unroll
    for (int f = 0; f < 4; ++f) {
        int t = f * 16 + c; if (t > 48) t = 48;
        const int tq = div7(t), tr = t - tq * 7;
        const unsigned short* base = qkv + (wbase + tq * WW + tr) * NQKV + h * 32 + qg * 8;
        aq[f] = *(const short8*)base;
        bk[f] = *(const short8*)(base + 256);
    }
    short8 bv[2][2];
    #pragma unroll
    for (int ks = 0; ks < 2; ++ks)
        #pragma unroll
        for (int i = 0; i < 8; ++i) {
            int pix = ks * 32 + qg * 8 + i; if (pix > 48) pix = 48;
            const int pd = div7(pix);
            const unsigned short* vp = qkv + (wbase + pd * WW + (pix - pd * 7)) * NQKV
                                           + 512 + h * 32 + c;
            bv[ks][0][i] = (short)vp[0];
            bv[ks][1][i] = (short)vp[16];
        }

    const float scale = 0.17677669529663687f;
    const float* bt = biasT + h * 4096;
    short* pw = PL + h * 16 * 72;

    #pragma unroll
    for (int fm = 0; fm < 4; ++fm) {
        f32x4 s[4];
        #pragma unroll
        for (int fj = 0; fj < 4; ++fj)
            s[fj] = __builtin_amdgcn_mfma_f32_16x16x32_bf16(aq[fm], bk[fj],
                                                            (f32x4){0.f,0.f,0.f,0.f}, 0, 0, 0);
        float p[4][4];
        #pragma unroll
        for (int reg = 0; reg < 4; ++reg) {
            const float* brow = bt + (fm * 16 + qg * 4 + reg) * 64;
            #pragma unroll
            for (int fj = 0; fj < 4; ++fj)
                p[fj][reg] = s[fj][reg] * scale + brow[fj * 16 + c];
        }
        float inv[4];
        #pragma unroll
        for (int reg = 0; reg < 4; ++reg) {
            float mx = fmaxf(fmaxf(p[0][reg], p[1][reg]), fmaxf(p[2][reg], p[3][reg]));
            mx = fmaxf(mx, __shfl_xor(mx, 1));
            mx = fmaxf(mx, __shfl_xor(mx, 2));
            mx = fmaxf(mx, __shfl_xor(mx, 4));
            mx = fmaxf(mx, __shfl_xor(mx, 8));
            float sum = 0.f;
            #pragma unroll
            for (int fj = 0; fj < 4; ++fj) {
                float e = __expf(p[fj][reg] - mx);
                p[fj][reg] = e; sum += e;
            }
            sum += __shfl_xor(sum, 1);
            sum += __shfl_xor(sum, 2);
            sum += __shfl_xor(sum, 4);
            sum += __shfl_xor(sum, 8);
            inv[reg] = 1.0f / sum;
        }
        #pragma unroll
        for (int fj = 0; fj < 4; ++fj)
            #pragma unroll
            for (int reg = 0; reg < 4; ++reg) {
                float v = p[fj][reg] * inv[reg];
                float o = __shfl_xor(v, 1);
                unsigned packed = (c & 1) ? pack2bf(o, v) : pack2bf(v, o);
                if ((c & 1) == 0)
                    *(unsigned*)&pw[(qg * 4 + reg) * 72 + fj * 16 + c] = packed;
            }
        short8 ap0 = *(const short8*)&pw[c * 72 + 0 * 32 + qg * 8];
        short8 ap1 = *(const short8*)&pw[c * 72 + 1 * 32 + qg * 8];
        #pragma unroll
        for (int fo = 0; fo < 2; ++fo) {
            f32x4 o4 = __builtin_amdgcn_mfma_f32_16x16x32_bf16(ap0, bv[0][fo],
                                                               (f32x4){0.f,0.f,0.f,0.f}, 0, 0, 0);
            o4 = __builtin_amdgcn_mfma_f32_16x16x32_bf16(ap1, bv[1][fo], o4, 0, 0, 0);
            #pragma unroll
            for (int reg = 0; reg < 4; ++reg) {
                int n = fm * 16 + qg * 4 + reg;
                if (n < 49) {
                    int nd = div7(n), nm = n - nd * 7;
                    obuf[(wbase + nd * WW + nm) * DIM + h * 32 + fo * 16 + c] =
                        (unsigned short)f2bf(o4[reg]);
                }
            }
        }
    }
}

// ---------------------------------------------------------------------------
// Kernel E (v3): same m97-style dbuf structure as qkv_gemm v5.
// out[b,c,p] += rate1 * (obuf @ proj_w^T + pb)
__global__ __launch_bounds__(256) void proj_gemm(const unsigned short* __restrict__ obuf,
                                                 const unsigned short* __restrict__ pwb,
                                                 const float* __restrict__ pb,
                                                 const float* __restrict__ rate1p,
                                                 float* __restrict__ out) {
    __shared__ __attribute__((aligned(16))) short M_lds[2][128 * 32];
    __shared__ __attribute__((aligned(16))) short C_lds[2][128 * 32];
    const int bidx = blockIdx.x;
    const int wg = (bidx & 7) * 98 + (bidx >> 3);   // grid 784 = 8*98
    const int ct = wg & 1, mt = wg >> 1;
    const int m0 = mt * 128, c0 = ct * 128;

    const int tid = threadIdx.x;
    const int lane = tid & 63;
    const int wave = tid >> 6;
    const int wr = wave >> 1, wc = wave & 1;
    const int r = lane & 15, q = lane >> 4;

    const unsigned short* mG[2];
    const unsigned short* cG[2];
    int lbase[2];
    #pragma unroll
    for (int t = 0; t < 2; ++t) {
        int ci = wave * 128 + t * 64 + lane;
        int srow = ci >> 2;
        int kgrp = (ci & 3) ^ (srow & 3);
        mG[t] = obuf + (size_t)(m0 + srow) * DIM + kgrp * 8;
        cG[t] = pwb  + (size_t)(c0 + srow) * DIM + kgrp * 8;
        lbase[t] = (wave * 128 + t * 64) * 8;
    }

    f32x4 acc[4][4];
    #pragma unroll
    for (int i = 0; i < 4; ++i)
        #pragma unroll
        for (int j = 0; j < 4; ++j) acc[i][j] = (f32x4){0.f, 0.f, 0.f, 0.f};

    #pragma unroll
    for (int t = 0; t < 2; ++t) {
        gld16(mG[t], (unsigned short*)&M_lds[0][lbase[t]]);
        gld16(cG[t], (unsigned short*)&C_lds[0][lbase[t]]);
    }
    __syncthreads();

    #pragma unroll
    for (int k = 0; k < 8; ++k) {
        const int buf = k & 1;
        if (k < 7) {
            const int k0 = (k + 1) * 32;
            #pragma unroll
            for (int t = 0; t < 2; ++t) {
                gld16(mG[t] + k0, (unsigned short*)&M_lds[buf ^ 1][lbase[t]]);
                gld16(cG[t] + k0, (unsigned short*)&C_lds[buf ^ 1][lbase[t]]);
            }
        }
        short8 cf[4], mf[4];
        #pragma unroll
        for (int f = 0; f < 4; ++f) {
            int crow = wr * 64 + f * 16 + r;
            cf[f] = *(const short8*)&C_lds[buf][crow * 32 + 8 * (q ^ (crow & 3))];
            int mrow = wc * 64 + f * 16 + r;
            mf[f] = *(const short8*)&M_lds[buf][mrow * 32 + 8 * (q ^ (mrow & 3))];
        }
        #pragma unroll
        for (int fc = 0; fc < 4; ++fc)
            #pragma unroll
            for (int fm2 = 0; fm2 < 4; ++fm2)
                acc[fc][fm2] = __builtin_amdgcn_mfma_f32_16x16x32_bf16(
                    cf[fc], mf[fm2], acc[fc][fm2], 0, 0, 0);
        __syncthreads();
    }

    const float r1 = rate1p[0];
    size_t boff[4];
    #pragma unroll
    for (int fm2 = 0; fm2 < 4; ++fm2) {
        int mb = m0 + wc * 64 + fm2 * 16 + r;
        boff[fm2] = (size_t)(mb / HWP) * DIM * HWP + (mb % HWP);
    }
    #pragma unroll
    for (int fc = 0; fc < 4; ++fc) {
        #pragma unroll
        for (int reg = 0; reg < 4; ++reg) {
            const int cc = c0 + wr * 64 + fc * 16 + q * 4 + reg;
            const float bias = pb[cc];
            #pragma unroll
            for (int fm2 = 0; fm2 < 4; ++fm2) {
                float* dst = out + boff[fm2] + (size_t)cc * HWP;
                *dst = *dst + r1 * (acc[fc][fm2][reg] + bias);
            }
        }
    }
}

// ---------------------------------------------------------------------------
extern "C" void kernel_launch(void* const* d_in, const int* in_sizes, int n_in,
                              void* d_out, int out_size, void* d_ws, size_t ws_size,
                              hipStream_t stream) {
    const float* x      = (const float*)d_in[0];
    const float* qkv_w  = (const float*)d_in[1];
    const float* qkv_b  = (const float*)d_in[2];
    const float* fc_w   = (const float*)d_in[3];
    const float* fc_b   = (const float*)d_in[4];
    const float* dep_w  = (const float*)d_in[5];
    const float* proj_w = (const float*)d_in[6];
    const float* proj_b = (const float*)d_in[7];
    const float* rpb    = (const float*)d_in[8];
    const float* rate1  = (const float*)d_in[9];
    const float* rate2  = (const float*)d_in[10];
    float* out = (float*)d_out;

    unsigned short* qkv   = (unsigned short*)d_ws;
    unsigned short* xt    = (unsigned short*)((char*)d_ws + XT_OFF);
    unsigned short* wqt   = (unsigned short*)((char*)d_ws + WQT_OFF);
    unsigned short* pwb   = (unsigned short*)((char*)d_ws + PWB_OFF);
    unsigned short* fconv = (unsigned short*)((char*)d_ws + FCONV_OFF);
    float*          biasT = (float*)((char*)d_ws + BIAS_OFF);
    unsigned short* obuf  = fconv;  // reused after conv_kernel consumes fconv

    xpose_kernel<<<dim3(7, 4, BATCH), 256, 0, stream>>>(x, xt);
    prep_kernel<<<dim3(72), 256, 0, stream>>>(qkv_w, proj_w, rpb, wqt, pwb, biasT);
    qkv_gemm<<<dim3(2352), 256, 0, stream>>>(xt, wqt, qkv_b, qkv);
    fc_kernel<<<dim3(HWP / 16, BATCH), 256, 0, stream>>>(qkv, fc_w, fc_b, fconv);
    conv_kernel<<<dim3(7, 32, BATCH), 256, 0, stream>>>(fconv, dep_w, rate2, out);
    attn_kernel<<<dim3(1024), 512, 0, stream>>>(qkv, biasT, obuf);
    proj_gemm<<<dim3(784), 256, 0, stream>>>(obuf, pwb, proj_b, rate1, out);
}

// Round 14
// 230.165 us; speedup vs baseline: 1.2578x; 1.0341x over previous
//
#include <hip/hip_runtime.h>

// Problem constants (B=16, DIM=256, H=W=56, NH=8, HD=32, WS=7)
#define BATCH 16
#define DIM 256
#define HH 56
#define WW 56
#define HWP 3136            // 56*56
#define M_TOT 50176         // BATCH*HWP
#define NQKV 768            // 3*DIM
#define NHEADS 8
#define HDIM 32
#define NWIN 49             // 7*7
// workspace offsets (bytes)
#define QKV_BYTES   77070336ull   // M_TOT*NQKV*2 (bf16)
#define XT_OFF      77070336ull
#define XT_BYTES    25690112ull   // M_TOT*DIM*2
#define WQT_OFF    102760448ull
#define PWB_OFF    103153664ull
#define FCONV_OFF  103284736ull   // bf16 fconv: 288*HWP*BATCH*2 = 28901376
#define BIAS_OFF   132186112ull   // f32 [8][64][64] = 131072 B

typedef float f32x4 __attribute__((ext_vector_type(4)));
typedef short short8 __attribute__((ext_vector_type(8)));
typedef unsigned short ushort4v __attribute__((ext_vector_type(4)));

__device__ __forceinline__ short f2bf(float f) {
    unsigned u = __float_as_uint(f);
    u += 0x7fffu + ((u >> 16) & 1u);   // RNE
    return (short)(u >> 16);
}
__device__ __forceinline__ float bf2f(unsigned short u) {
    return __uint_as_float(((unsigned)u) << 16);
}
__device__ __forceinline__ unsigned pack2bf(float lo, float hi) {
    unsigned ul = __float_as_uint(lo); ul += 0x7fffu + ((ul >> 16) & 1u);
    unsigned uh = __float_as_uint(hi); uh += 0x7fffu + ((uh >> 16) & 1u);
    return (ul >> 16) | (uh & 0xffff0000u);
}
__device__ __forceinline__ int div7(int n) { return (n * 9363) >> 16; }  // exact for 0..63

// async global->LDS, 16B per lane; LDS dest = uniform base + lane*16
__device__ __forceinline__ void gld16(const unsigned short* g, unsigned short* l) {
    __builtin_amdgcn_global_load_lds(
        (const __attribute__((address_space(1))) void*)g,
        (__attribute__((address_space(3))) void*)l, 16, 0, 0);
}

// ---------------------------------------------------------------------------
// Kernel T0: x (B,C,HW) fp32 -> xt (B*HW, C) bf16.
__global__ __launch_bounds__(256) void xpose_kernel(const float* __restrict__ x,
                                                    unsigned short* __restrict__ xt) {
    __shared__ unsigned short tls[64 * 448];   // [ch][px'] swizzled, 56 KB
    const int tid = threadIdx.x;
    const int p0 = blockIdx.x * 448;
    const int k0 = blockIdx.y * 64;
    const int b  = blockIdx.z;
    const float* xb = x + ((size_t)b * DIM + k0) * HWP + p0;
    #pragma unroll
    for (int pass = 0; pass < 28; ++pass) {
        int idx = tid + pass * 256;            // float4 index (64*112 total)
        int ch = idx / 112, px4 = idx - ch * 112;
        float4 v = *(const float4*)(xb + (size_t)ch * HWP + px4 * 4);
        int px4s = px4 ^ ((ch >> 3) & 7);
        ushort4v s;
        s[0] = (unsigned short)f2bf(v.x); s[1] = (unsigned short)f2bf(v.y);
        s[2] = (unsigned short)f2bf(v.z); s[3] = (unsigned short)f2bf(v.w);
        *(ushort4v*)&tls[ch * 448 + px4s * 4] = s;
    }
    __syncthreads();
    unsigned short* xto = xt + ((size_t)b * HWP + p0) * DIM + k0;
    #pragma unroll
    for (int q = 0; q < 14; ++q) {
        int idx = tid + q * 256;               // uint4 index (3584 total)
        int px = idx >> 3, j8 = (idx & 7) * 8;
        int key = (j8 >> 3) & 7;
        int pxs = ((px >> 2) ^ key) * 4 + (px & 3);
        unsigned r[4];
        #pragma unroll
        for (int jj = 0; jj < 4; ++jj) {
            unsigned lo = tls[(j8 + 2 * jj) * 448 + pxs];
            unsigned hi = tls[(j8 + 2 * jj + 1) * 448 + pxs];
            r[jj] = lo | (hi << 16);
        }
        uint4 o; o.x = r[0]; o.y = r[1]; o.z = r[2]; o.w = r[3];
        *(uint4*)(xto + (size_t)px * DIM + j8) = o;
    }
}

// ---------------------------------------------------------------------------
// Kernel T1: blocks 0..47: wq -> wqt (j,k) bf16; 48..63: proj_w cast;
//            blocks 64..71: bias table biasT[h][64][64] f32, PRE-SCALED by
//            log2(e) so attn does p = exp2(s*cst + bias).
__global__ __launch_bounds__(256) void prep_kernel(const float* __restrict__ wq,
                                                   const float* __restrict__ pw,
                                                   const float* __restrict__ rpb,
                                                   unsigned short* __restrict__ wqt,
                                                   unsigned short* __restrict__ pwb,
                                                   float* __restrict__ biasT) {
    const int tid = threadIdx.x;
    const int bid = blockIdx.x;
    if (bid < 48) {
        __shared__ float t[64][65];
        const int j0 = (bid >> 2) * 64, k0 = (bid & 3) * 64;
        #pragma unroll
        for (int kk = tid >> 6; kk < 64; kk += 4)
            t[kk][tid & 63] = wq[(size_t)(k0 + kk) * NQKV + j0 + (tid & 63)];
        __syncthreads();
        const int jj = tid >> 2, c16 = (tid & 3) * 16;
        unsigned short* dst = wqt + (size_t)(j0 + jj) * DIM + k0 + c16;
        #pragma unroll
        for (int i = 0; i < 16; ++i) dst[i] = (unsigned short)f2bf(t[c16 + i][jj]);
    } else if (bid < 64) {
        const int base = (bid - 48) * 4096 + tid;
        #pragma unroll
        for (int i = 0; i < 16; ++i)
            pwb[base + i * 256] = (unsigned short)f2bf(pw[base + i * 256]);
    } else {
        const int h = bid - 64;
        #pragma unroll
        for (int i = 0; i < 16; ++i) {
            int idx = tid + i * 256;
            int n = idx >> 6, m = idx & 63;
            float v = -1e30f;
            if (n < 49 && m < 49) {
                int nd = div7(n), md = div7(m);
                int ii = (nd - md + 6) * 13 + ((n - nd * 7) - (m - md * 7) + 6);
                v = rpb[ii * NHEADS + h] * 1.4426950408889634f;
            }
            biasT[h * 4096 + idx] = v;
        }
    }
}

// ---------------------------------------------------------------------------
// Kernel A (v5): m97-style dbuf GEMM, BK=32, global_load_lds width-16 staging.
__global__ __launch_bounds__(256) void qkv_gemm(const unsigned short* __restrict__ xt,
                                                const unsigned short* __restrict__ wqt,
                                                const float* __restrict__ bq,
                                                unsigned short* __restrict__ qkv) {
    __shared__ __attribute__((aligned(16))) short A_lds[2][128 * 32];  // 16 KB
    __shared__ __attribute__((aligned(16))) short B_lds[2][128 * 32];  // 16 KB
    const int bidx = blockIdx.x;
    const int wg = (bidx & 7) * 294 + (bidx >> 3);
    const int jt = wg % 6, mt = wg / 6;
    const int m0 = mt * 128, j0 = jt * 128;

    const int tid = threadIdx.x;
    const int lane = tid & 63;
    const int wave = tid >> 6;
    const int wr = wave >> 1, wc = wave & 1;
    const int r = lane & 15, q = lane >> 4;

    const unsigned short* aG[2];
    const unsigned short* bG[2];
    int lbase[2];
    #pragma unroll
    for (int t = 0; t < 2; ++t) {
        int ci = wave * 128 + t * 64 + lane;
        int srow = ci >> 2;
        int kgrp = (ci & 3) ^ (srow & 3);
        aG[t] = xt  + (size_t)(m0 + srow) * DIM + kgrp * 8;
        bG[t] = wqt + (size_t)(j0 + srow) * DIM + kgrp * 8;
        lbase[t] = (wave * 128 + t * 64) * 8;   // shorts
    }

    f32x4 acc[4][4];
    #pragma unroll
    for (int i = 0; i < 4; ++i)
        #pragma unroll
        for (int j = 0; j < 4; ++j) acc[i][j] = (f32x4){0.f, 0.f, 0.f, 0.f};

    #pragma unroll
    for (int t = 0; t < 2; ++t) {
        gld16(aG[t], (unsigned short*)&A_lds[0][lbase[t]]);
        gld16(bG[t], (unsigned short*)&B_lds[0][lbase[t]]);
    }
    __syncthreads();

    #pragma unroll
    for (int k = 0; k < 8; ++k) {
        const int buf = k & 1;
        if (k < 7) {
            const int k0 = (k + 1) * 32;
            #pragma unroll
            for (int t = 0; t < 2; ++t) {
                gld16(aG[t] + k0, (unsigned short*)&A_lds[buf ^ 1][lbase[t]]);
                gld16(bG[t] + k0, (unsigned short*)&B_lds[buf ^ 1][lbase[t]]);
            }
        }
        short8 af[4], bfr[4];
        #pragma unroll
        for (int f = 0; f < 4; ++f) {
            int mrow = wr * 64 + f * 16 + r;
            af[f] = *(const short8*)&A_lds[buf][mrow * 32 + 8 * (q ^ (mrow & 3))];
            int nrow = wc * 64 + f * 16 + r;
            bfr[f] = *(const short8*)&B_lds[buf][nrow * 32 + 8 * (q ^ (nrow & 3))];
        }
        #pragma unroll
        for (int fm = 0; fm < 4; ++fm)
            #pragma unroll
            for (int fj = 0; fj < 4; ++fj)
                acc[fm][fj] = __builtin_amdgcn_mfma_f32_16x16x32_bf16(
                    af[fm], bfr[fj], acc[fm][fj], 0, 0, 0);
        __syncthreads();
    }

    #pragma unroll
    for (int fm = 0; fm < 4; ++fm) {
        const int mbase = m0 + wr * 64 + fm * 16 + q * 4;
        #pragma unroll
        for (int fj = 0; fj < 4; ++fj) {
            const int j = j0 + wc * 64 + fj * 16 + r;
            const float bias = bq[j];
            unsigned short* op = qkv + (size_t)mbase * NQKV + j;
            #pragma unroll
            for (int rg = 0; rg < 4; ++rg)
                op[(size_t)rg * NQKV] = (unsigned short)f2bf(acc[fm][fj][rg] + bias);
        }
    }
}

// ---------------------------------------------------------------------------
// Kernel B: f_conv[b, g*9+o, p] = sum_c fc_w[o,c]*bf2f(qkv[b,p,c*32+g]) + fc_b[o]
__global__ __launch_bounds__(256) void fc_kernel(const unsigned short* __restrict__ qkv,
                                                 const float* __restrict__ fc_w,
                                                 const float* __restrict__ fc_b,
                                                 unsigned short* __restrict__ fconv) {
    __shared__ unsigned short f[16 * 768];   // 24 KB
    __shared__ float ob[16][289];
    __shared__ float w[9][24];
    __shared__ float bsh[9];
    const int tid = threadIdx.x;
    if (tid < 216) w[tid / 24][tid % 24] = fc_w[tid];
    if (tid < 9) bsh[tid] = fc_b[tid];
    const int p0 = blockIdx.x * 16;
    const int b  = blockIdx.y;
    const uint4* src = (const uint4*)(qkv + ((size_t)b * HWP + p0) * NQKV);
    uint4* dstf = (uint4*)f;
    #pragma unroll
    for (int i = 0; i < 6; ++i) dstf[tid + i * 256] = src[tid + i * 256];
    __syncthreads();
    #pragma unroll
    for (int it = 0; it < 2; ++it) {
        const int item = tid + it * 256;
        const int pp = item >> 5, g = item & 31;
        const unsigned short* fr = f + pp * 768 + g;
        float acc[9];
        #pragma unroll
        for (int o = 0; o < 9; ++o) acc[o] = bsh[o];
        #pragma unroll
        for (int c = 0; c < 24; ++c) {
            float v = bf2f(fr[c * 32]);
            #pragma unroll
            for (int o = 0; o < 9; ++o) acc[o] += w[o][c] * v;
        }
        #pragma unroll
        for (int o = 0; o < 9; ++o) ob[pp][g * 9 + o] = acc[o];
    }
    __syncthreads();
    unsigned short* og = fconv + (size_t)b * 288 * HWP + p0;
    for (int i = tid; i < 288 * 16; i += 256) {
        int ch = i >> 4, pp = i & 15;
        og[(size_t)ch * HWP + pp] = (unsigned short)f2bf(ob[pp][ch]);
    }
}

// ---------------------------------------------------------------------------
// Kernel C (v4): grouped 3x3 conv, lane = output column.
__global__ __launch_bounds__(256) void conv_kernel(const unsigned short* __restrict__ fconv,
                                                   const float* __restrict__ dep_w,
                                                   const float* __restrict__ rate2p,
                                                   float* __restrict__ out) {
    __shared__ unsigned short hal[9][10][64];  // 11520 B
    __shared__ float wfl[81][8];               // [o*9+ky*3+kx][c8]
    const int tid = threadIdx.x;
    const int strip = blockIdx.x;              // 0..6 (8 rows each)
    const int g = blockIdx.y, b = blockIdx.z;

    for (int i = tid; i < 648; i += 256) {
        int ok = i >> 3, c8 = i & 7;
        wfl[ok][c8] = dep_w[(size_t)(g * 8 + c8) * 81 + ok];
    }
    const unsigned short* fp = fconv + ((size_t)b * 288 + g * 9) * HWP;
    const int y0 = strip * 8 - 1;
    for (int i = tid; i < 5760; i += 256) {
        int col = i & 63;
        int rest = i >> 6;                     // 0..89
        int o = rest / 10, y = rest - o * 10;
        int gy = y0 + y, gx = col - 1;
        unsigned short v = 0;
        if (gy >= 0 && gy < HH && (unsigned)gx < WW)
            v = fp[(size_t)o * HWP + gy * WW + gx];
        hal[o][y][col] = v;
    }
    __syncthreads();

    const int x = tid & 63;
    const int w = tid >> 6;                    // wave -> out rows 2w, 2w+1
    const int e = x & ~1;
    const bool odd = (x & 1) != 0;
    float acc[2][8] = {};
    for (int o = 0; o < 9; ++o) {
        float V[4][3];
        #pragma unroll
        for (int h = 0; h < 4; ++h) {
            const unsigned short* hr = &hal[o][2 * w + h][e];
            unsigned D0 = *(const unsigned*)hr;
            unsigned D1 = *(const unsigned*)(hr + 2);
            float a0 = __uint_as_float(D0 << 16);
            float a1 = __uint_as_float(D0 & 0xffff0000u);
            float a2 = __uint_as_float(D1 << 16);
            float a3 = __uint_as_float(D1 & 0xffff0000u);
            V[h][0] = odd ? a1 : a0;
            V[h][1] = odd ? a2 : a1;
            V[h][2] = odd ? a3 : a2;
        }
        #pragma unroll
        for (int ky = 0; ky < 3; ++ky)
            #pragma unroll
            for (int kx = 0; kx < 3; ++kx) {
                f32x4 w0 = *(const f32x4*)&wfl[o * 9 + ky * 3 + kx][0];
                f32x4 w1 = *(const f32x4*)&wfl[o * 9 + ky * 3 + kx][4];
                #pragma unroll
                for (int j = 0; j < 2; ++j) {
                    const float vv = V[j + ky][kx];
                    acc[j][0] += vv * w0[0]; acc[j][1] += vv * w0[1];
                    acc[j][2] += vv * w0[2]; acc[j][3] += vv * w0[3];
                    acc[j][4] += vv * w1[0]; acc[j][5] += vv * w1[1];
                    acc[j][6] += vv * w1[2]; acc[j][7] += vv * w1[3];
                }
            }
    }
    if (x < WW) {
        const float r2 = rate2p[0];
        #pragma unroll
        for (int j = 0; j < 2; ++j) {
            const int y = strip * 8 + 2 * w + j;
            #pragma unroll
            for (int c8 = 0; c8 < 8; ++c8)
                out[((size_t)b * DIM + g * 8 + c8) * HWP + y * WW + x] = r2 * acc[j][c8];
        }
    }
}

// ---------------------------------------------------------------------------
// Kernel D (v3): no-max softmax via exp2 with pre-scaled bias; normalization
// deferred to the PV output. V direct from global; LDS = PL only; no barriers.
__global__ __launch_bounds__(512) void attn_kernel(const unsigned short* __restrict__ qkv,
                                                   const float* __restrict__ biasT,
                                                   unsigned short* __restrict__ obuf) {
    __shared__ __attribute__((aligned(16))) short PL[8 * 16 * 72]; // per-wave [16][72] 18 KB
    const int tid = threadIdx.x;
    const int win = blockIdx.x;
    const int b = win >> 6, wrw = win & 63;
    const int wy = wrw >> 3, wx = wrw & 7;
    const size_t wbase = (size_t)b * HWP + (size_t)(wy * 7) * WW + wx * 7;

    const int lane = tid & 63;
    const int h = tid >> 6;
    const int c = lane & 15, qg = lane >> 4;

    short8 aq[4], bk[4];
    #pragma unroll
    for (int f = 0; f < 4; ++f) {
        int t = f * 16 + c; if (t > 48) t = 48;
        const int tq = div7(t), tr = t - tq * 7;
        const unsigned short* base = qkv + (wbase + tq * WW + tr) * NQKV + h * 32 + qg * 8;
        aq[f] = *(const short8*)base;
        bk[f] = *(const short8*)(base + 256);
    }
    short8 bv[2][2];
    #pragma unroll
    for (int ks = 0; ks < 2; ++ks)
        #pragma unroll
        for (int i = 0; i < 8; ++i) {
            int pix = ks * 32 + qg * 8 + i; if (pix > 48) pix = 48;
            const int pd = div7(pix);
            const unsigned short* vp = qkv + (wbase + pd * WW + (pix - pd * 7)) * NQKV
                                           + 512 + h * 32 + c;
            bv[ks][0][i] = (short)vp[0];
            bv[ks][1][i] = (short)vp[16];
        }

    const float cst = 0.25503766727f;   // 32^-0.5 * log2(e)
    const float* bt = biasT + h * 4096;
    short* pw = PL + h * 16 * 72;

    #pragma unroll
    for (int fm = 0; fm < 4; ++fm) {
        f32x4 s[4];
        #pragma unroll
        for (int fj = 0; fj < 4; ++fj)
            s[fj] = __builtin_amdgcn_mfma_f32_16x16x32_bf16(aq[fm], bk[fj],
                                                            (f32x4){0.f,0.f,0.f,0.f}, 0, 0, 0);
        // p = 2^(s*cst + bias)  -- no max-subtract (|arg| <~ 15, safe in f32)
        float p[4][4];
        #pragma unroll
        for (int reg = 0; reg < 4; ++reg) {
            const float* brow = bt + (fm * 16 + qg * 4 + reg) * 64;
            #pragma unroll
            for (int fj = 0; fj < 4; ++fj)
                p[fj][reg] = exp2f(s[fj][reg] * cst + brow[fj * 16 + c]);
        }
        // row sums (over fj in-lane, over c via shfl); normalization deferred
        float inv[4];
        #pragma unroll
        for (int reg = 0; reg < 4; ++reg) {
            float sum = (p[0][reg] + p[1][reg]) + (p[2][reg] + p[3][reg]);
            sum += __shfl_xor(sum, 1);
            sum += __shfl_xor(sum, 2);
            sum += __shfl_xor(sum, 4);
            sum += __shfl_xor(sum, 8);
            inv[reg] = 1.0f / sum;
        }
        // pack unnormalized P to bf16 pairs -> per-wave PL
        #pragma unroll
        for (int fj = 0; fj < 4; ++fj)
            #pragma unroll
            for (int reg = 0; reg < 4; ++reg) {
                float v = p[fj][reg];
                float o = __shfl_xor(v, 1);
                unsigned packed = (c & 1) ? pack2bf(o, v) : pack2bf(v, o);
                if ((c & 1) == 0)
                    *(unsigned*)&pw[(qg * 4 + reg) * 72 + fj * 16 + c] = packed;
            }
        short8 ap0 = *(const short8*)&pw[c * 72 + 0 * 32 + qg * 8];
        short8 ap1 = *(const short8*)&pw[c * 72 + 1 * 32 + qg * 8];
        #pragma unroll
        for (int fo = 0; fo < 2; ++fo) {
            f32x4 o4 = __builtin_amdgcn_mfma_f32_16x16x32_bf16(ap0, bv[0][fo],
                                                               (f32x4){0.f,0.f,0.f,0.f}, 0, 0, 0);
            o4 = __builtin_amdgcn_mfma_f32_16x16x32_bf16(ap1, bv[1][fo], o4, 0, 0, 0);
            #pragma unroll
            for (int reg = 0; reg < 4; ++reg) {
                int n = fm * 16 + qg * 4 + reg;
                if (n < 49) {
                    int nd = div7(n), nm = n - nd * 7;
                    obuf[(wbase + nd * WW + nm) * DIM + h * 32 + fo * 16 + c] =
                        (unsigned short)f2bf(o4[reg] * inv[reg]);
                }
            }
        }
    }
}

// ---------------------------------------------------------------------------
// Kernel E (v3): dbuf gld16 GEMM. out[b,c,p] += rate1 * (obuf @ proj_w^T + pb)
__global__ __launch_bounds__(256) void proj_gemm(const unsigned short* __restrict__ obuf,
                                                 const unsigned short* __restrict__ pwb,
                                                 const float* __restrict__ pb,
                                                 const float* __restrict__ rate1p,
                                                 float* __restrict__ out) {
    __shared__ __attribute__((aligned(16))) short M_lds[2][128 * 32];
    __shared__ __attribute__((aligned(16))) short C_lds[2][128 * 32];
    const int bidx = blockIdx.x;
    const int wg = (bidx & 7) * 98 + (bidx >> 3);   // grid 784 = 8*98
    const int ct = wg & 1, mt = wg >> 1;
    const int m0 = mt * 128, c0 = ct * 128;

    const int tid = threadIdx.x;
    const int lane = tid & 63;
    const int wave = tid >> 6;
    const int wr = wave >> 1, wc = wave & 1;
    const int r = lane & 15, q = lane >> 4;

    const unsigned short* mG[2];
    const unsigned short* cG[2];
    int lbase[2];
    #pragma unroll
    for (int t = 0; t < 2; ++t) {
        int ci = wave * 128 + t * 64 + lane;
        int srow = ci >> 2;
        int kgrp = (ci & 3) ^ (srow & 3);
        mG[t] = obuf + (size_t)(m0 + srow) * DIM + kgrp * 8;
        cG[t] = pwb  + (size_t)(c0 + srow) * DIM + kgrp * 8;
        lbase[t] = (wave * 128 + t * 64) * 8;
    }

    f32x4 acc[4][4];
    #pragma unroll
    for (int i = 0; i < 4; ++i)
        #pragma unroll
        for (int j = 0; j < 4; ++j) acc[i][j] = (f32x4){0.f, 0.f, 0.f, 0.f};

    #pragma unroll
    for (int t = 0; t < 2; ++t) {
        gld16(mG[t], (unsigned short*)&M_lds[0][lbase[t]]);
        gld16(cG[t], (unsigned short*)&C_lds[0][lbase[t]]);
    }
    __syncthreads();

    #pragma unroll
    for (int k = 0; k < 8; ++k) {
        const int buf = k & 1;
        if (k < 7) {
            const int k0 = (k + 1) * 32;
            #pragma unroll
            for (int t = 0; t < 2; ++t) {
                gld16(mG[t] + k0, (unsigned short*)&M_lds[buf ^ 1][lbase[t]]);
                gld16(cG[t] + k0, (unsigned short*)&C_lds[buf ^ 1][lbase[t]]);
            }
        }
        short8 cf[4], mf[4];
        #pragma unroll
        for (int f = 0; f < 4; ++f) {
            int crow = wr * 64 + f * 16 + r;
            cf[f] = *(const short8*)&C_lds[buf][crow * 32 + 8 * (q ^ (crow & 3))];
            int mrow = wc * 64 + f * 16 + r;
            mf[f] = *(const short8*)&M_lds[buf][mrow * 32 + 8 * (q ^ (mrow & 3))];
        }
        #pragma unroll
        for (int fc = 0; fc < 4; ++fc)
            #pragma unroll
            for (int fm2 = 0; fm2 < 4; ++fm2)
                acc[fc][fm2] = __builtin_amdgcn_mfma_f32_16x16x32_bf16(
                    cf[fc], mf[fm2], acc[fc][fm2], 0, 0, 0);
        __syncthreads();
    }

    const float r1 = rate1p[0];
    size_t boff[4];
    #pragma unroll
    for (int fm2 = 0; fm2 < 4; ++fm2) {
        int mb = m0 + wc * 64 + fm2 * 16 + r;
        boff[fm2] = (size_t)(mb / HWP) * DIM * HWP + (mb % HWP);
    }
    #pragma unroll
    for (int fc = 0; fc < 4; ++fc) {
        #pragma unroll
        for (int reg = 0; reg < 4; ++reg) {
            const int cc = c0 + wr * 64 + fc * 16 + q * 4 + reg;
            const float bias = pb[cc];
            #pragma unroll
            for (int fm2 = 0; fm2 < 4; ++fm2) {
                float* dst = out + boff[fm2] + (size_t)cc * HWP;
                *dst = *dst + r1 * (acc[fc][fm2][reg] + bias);
            }
        }
    }
}

// ---------------------------------------------------------------------------
extern "C" void kernel_launch(void* const* d_in, const int* in_sizes, int n_in,
                              void* d_out, int out_size, void* d_ws, size_t ws_size,
                              hipStream_t stream) {
    const float* x      = (const float*)d_in[0];
    const float* qkv_w  = (const float*)d_in[1];
    const float* qkv_b  = (const float*)d_in[2];
    const float* fc_w   = (const float*)d_in[3];
    const float* fc_b   = (const float*)d_in[4];
    const float* dep_w  = (const float*)d_in[5];
    const float* proj_w = (const float*)d_in[6];
    const float* proj_b = (const float*)d_in[7];
    const float* rpb    = (const float*)d_in[8];
    const float* rate1  = (const float*)d_in[9];
    const float* rate2  = (const float*)d_in[10];
    float* out = (float*)d_out;

    unsigned short* qkv   = (unsigned short*)d_ws;
    unsigned short* xt    = (unsigned short*)((char*)d_ws + XT_OFF);
    unsigned short* wqt   = (unsigned short*)((char*)d_ws + WQT_OFF);
    unsigned short* pwb   = (unsigned short*)((char*)d_ws + PWB_OFF);
    unsigned short* fconv = (unsigned short*)((char*)d_ws + FCONV_OFF);
    float*          biasT = (float*)((char*)d_ws + BIAS_OFF);
    unsigned short* obuf  = fconv;  // reused after conv_kernel consumes fconv

    xpose_kernel<<<dim3(7, 4, BATCH), 256, 0, stream>>>(x, xt);
    prep_kernel<<<dim3(72), 256, 0, stream>>>(qkv_w, proj_w, rpb, wqt, pwb, biasT);
    qkv_gemm<<<dim3(2352), 256, 0, stream>>>(xt, wqt, qkv_b, qkv);
    fc_kernel<<<dim3(HWP / 16, BATCH), 256, 0, stream>>>(qkv, fc_w, fc_b, fconv);
    conv_kernel<<<dim3(7, 32, BATCH), 256, 0, stream>>>(fconv, dep_w, rate2, out);
    attn_kernel<<<dim3(1024), 512, 0, stream>>>(qkv, biasT, obuf);
    proj_gemm<<<dim3(784), 256, 0, stream>>>(obuf, pwb, proj_b, rate1, out);
}